// Round 1
// baseline (84.843 us; speedup 1.0000x reference)
//
#include <hip/hip_runtime.h>

#define NN 1024
#define EE 64

// K1: base[i][e] = x[i]*W1[e] + b1[e] + sum_j relu(cost[j][i]*w4[e] + b4[e])
// grid (16 i-tiles, 16 j-chunks), block 256 = 64 i-lanes x 4 e-groups(16 e each)
__global__ __launch_bounds__(256) void k1_base(
    const float* __restrict__ nf, const float* __restrict__ cost,
    const float* __restrict__ W1, const float* __restrict__ b1,
    const float* __restrict__ w4, const float* __restrict__ b4,
    float* __restrict__ base)
{
    const int it = blockIdx.x;
    const int jc = blockIdx.y;
    const int tid = threadIdx.x;
    const int il = tid & 63;
    const int eg = tid >> 6;
    const int i = it * 64 + il;
    const int j0 = jc * 64;

    float w4v[16], b4v[16];
#pragma unroll
    for (int ee = 0; ee < 16; ++ee) {
        int e = eg * 16 + ee;
        w4v[ee] = w4[e];
        b4v[ee] = b4[e];
    }

    float acc[16];
    if (jc == 0) {
        float xi = nf[i];
#pragma unroll
        for (int ee = 0; ee < 16; ++ee) {
            int e = eg * 16 + ee;
            acc[ee] = fmaf(xi, W1[e], b1[e]);
        }
    } else {
#pragma unroll
        for (int ee = 0; ee < 16; ++ee) acc[ee] = 0.f;
    }

    for (int jj = 0; jj < 64; ++jj) {
        float cv = cost[(size_t)(j0 + jj) * NN + i];
#pragma unroll
        for (int ee = 0; ee < 16; ++ee) {
            acc[ee] += fmaxf(fmaf(cv, w4v[ee], b4v[ee]), 0.f);
        }
    }
#pragma unroll
    for (int ee = 0; ee < 16; ++ee) {
        atomicAdd(&base[(size_t)i * EE + eg * 16 + ee], acc[ee]);
    }
}

// K2: 4-step scan collapsed to E-vector recurrence; single 1024-thread block.
// thread t: column c = t&63, row-group g = t>>6 (16 groups x 64 rows).
__global__ __launch_bounds__(1024) void k2_scan(
    const float* __restrict__ base,
    const float* __restrict__ W2, const float* __restrict__ b2,
    const float* __restrict__ W5,
    const float* __restrict__ W6, const float* __restrict__ b6,
    float* __restrict__ v2out, float* __restrict__ Cout)
{
    __shared__ float sP[1024];
    __shared__ float sS[64];
    __shared__ float sV[64];
    const int tid = threadIdx.x;
    const int c = tid & 63;
    const int g = tid >> 6;

    // cache this thread's 64 base values in registers
    float bl[64];
#pragma unroll
    for (int rr = 0; rr < 64; ++rr)
        bl[rr] = base[(size_t)(g * 64 + rr) * EE + c];

    if (tid < 64) sS[c] = 0.f;
    __syncthreads();

    for (int t = 0; t < 4; ++t) {
        // v2 = W2 @ s + b2 (wave 0 only; s_0 = 0 so first iter v2 = b2)
        if (tid < 64) {
            float v = b2[c];
            for (int k = 0; k < 64; ++k) v = fmaf(W2[c * 64 + k], sS[k], v);
            sV[c] = v;
        }
        __syncthreads();
        float v2c = sV[c];
        float acc = 0.f;
#pragma unroll
        for (int rr = 0; rr < 64; ++rr) acc += fmaxf(bl[rr] + v2c, 0.f);
        sP[tid] = acc;
        __syncthreads();
        if (tid < 64) {
            float s = 0.f;
#pragma unroll
            for (int gg = 0; gg < 16; ++gg) s += sP[gg * 64 + c];
            sS[c] = s;
        }
        __syncthreads();
    }

    if (tid < 64) {
        // h1 = W6 @ s4 + b6 ; C = sum_e relu(h1[e]) * W5[0][e]
        float h = b6[c];
        for (int k = 0; k < 64; ++k) h = fmaf(W6[c * 64 + k], sS[k], h);
        float p = fmaxf(h, 0.f) * W5[c];
#pragma unroll
        for (int off = 32; off > 0; off >>= 1) p += __shfl_down(p, off, 64);
        v2out[c] = sV[c];
        if (tid == 0) Cout[0] = p;
    }
}

// K3: per-row epilogue. 4 rows per block (one wave per row).
__global__ __launch_bounds__(256) void k3_out(
    const float* __restrict__ base,
    const float* __restrict__ W7, const float* __restrict__ b7,
    const float* __restrict__ W5, const float* __restrict__ b5,
    const float* __restrict__ v2, const float* __restrict__ Cin,
    float* __restrict__ q)
{
    __shared__ float W7L[64 * 65];
    __shared__ float embL[4 * 64];
    const int tid = threadIdx.x;
    const int lane = tid & 63;
    const int rl = tid >> 6;
    const int i = blockIdx.x * 4 + rl;

    for (int m = tid; m < 4096; m += 256)
        W7L[(m >> 6) * 65 + (m & 63)] = W7[m];

    float ev = fmaxf(base[(size_t)i * EE + lane] + v2[lane], 0.f);
    embL[rl * 64 + lane] = ev;
    __syncthreads();

    float h = b7[lane];
#pragma unroll
    for (int k = 0; k < 64; ++k)
        h = fmaf(embL[rl * 64 + k], W7L[lane * 65 + k], h);
    float p = fmaxf(h, 0.f) * W5[64 + lane];
#pragma unroll
    for (int off = 32; off > 0; off >>= 1) p += __shfl_down(p, off, 64);
    if (lane == 0) q[i] = p + Cin[0] + b5[0];
}

extern "C" void kernel_launch(void* const* d_in, const int* in_sizes, int n_in,
                              void* d_out, int out_size, void* d_ws, size_t ws_size,
                              hipStream_t stream)
{
    (void)in_sizes; (void)n_in; (void)out_size; (void)ws_size;
    const float* nf   = (const float*)d_in[0];
    const float* cost = (const float*)d_in[1];
    const float* W1   = (const float*)d_in[2];
    const float* b1   = (const float*)d_in[3];
    const float* W2   = (const float*)d_in[4];
    const float* b2   = (const float*)d_in[5];
    const float* w4   = (const float*)d_in[6];
    const float* b4   = (const float*)d_in[7];
    const float* W5   = (const float*)d_in[8];
    const float* b5   = (const float*)d_in[9];
    const float* W6   = (const float*)d_in[10];
    const float* b6   = (const float*)d_in[11];
    const float* W7   = (const float*)d_in[12];
    const float* b7   = (const float*)d_in[13];
    float* q    = (float*)d_out;
    float* base = (float*)d_ws;            // N*E floats
    float* v2o  = base + (size_t)NN * EE;  // E floats
    float* Co   = v2o + EE;                // 1 float

    hipMemsetAsync(base, 0, (size_t)NN * EE * sizeof(float), stream);

    dim3 g1(16, 16);
    k1_base<<<g1, 256, 0, stream>>>(nf, cost, W1, b1, w4, b4, base);
    k2_scan<<<1, 1024, 0, stream>>>(base, W2, b2, W5, W6, b6, v2o, Co);
    k3_out<<<256, 256, 0, stream>>>(base, W7, b7, W5, b5, v2o, Co, q);
}

// Round 2
// 77.729 us; speedup vs baseline: 1.0915x; 1.0915x over previous
//
#include <hip/hip_runtime.h>

#define NN 1024
#define EE 64
#define JC 32

// K1: base[i][e] = x[i]*W1[e] + b1[e] + sum_j relu(cost[j][i]*w4[e] + b4[e])
// grid (32 i-tiles, 32 j-chunks), block 256 = 32 i-lanes x 8 e-groups(8 e each)
__global__ __launch_bounds__(256) void k1_base(
    const float* __restrict__ nf, const float* __restrict__ cost,
    const float* __restrict__ W1, const float* __restrict__ b1,
    const float* __restrict__ w4, const float* __restrict__ b4,
    float* __restrict__ base)
{
    const int it = blockIdx.x;
    const int jc = blockIdx.y;
    const int tid = threadIdx.x;
    const int il = tid & 31;
    const int eg = tid >> 5;          // 8 e-groups of 8
    const int i = it * 32 + il;
    const int j0 = jc * JC;

    float w4v[8], b4v[8];
#pragma unroll
    for (int ee = 0; ee < 8; ++ee) {
        int e = eg * 8 + ee;
        w4v[ee] = w4[e];
        b4v[ee] = b4[e];
    }

    float acc[8];
    if (jc == 0) {
        float xi = nf[i];
#pragma unroll
        for (int ee = 0; ee < 8; ++ee) {
            int e = eg * 8 + ee;
            acc[ee] = fmaf(xi, W1[e], b1[e]);
        }
    } else {
#pragma unroll
        for (int ee = 0; ee < 8; ++ee) acc[ee] = 0.f;
    }

    const float* cp = cost + (size_t)j0 * NN + i;
#pragma unroll 8
    for (int jj = 0; jj < JC; ++jj) {
        float cv = cp[(size_t)jj * NN];
#pragma unroll
        for (int ee = 0; ee < 8; ++ee)
            acc[ee] += fmaxf(fmaf(cv, w4v[ee], b4v[ee]), 0.f);
    }

#pragma unroll
    for (int ee = 0; ee < 8; ++ee)
        atomicAdd(&base[(size_t)i * EE + eg * 8 + ee], acc[ee]);
}

// K2: 4-step scan collapsed to E-vector recurrence; single 1024-thread block.
__global__ __launch_bounds__(1024) void k2_scan(
    const float* __restrict__ base,
    const float* __restrict__ W2, const float* __restrict__ b2,
    const float* __restrict__ W5,
    const float* __restrict__ W6, const float* __restrict__ b6,
    float* __restrict__ v2out, float* __restrict__ Cout)
{
    __shared__ float W2L[64 * 65];
    __shared__ float sP[1024];
    __shared__ float sS[64];
    __shared__ float sV[64];
    const int tid = threadIdx.x;
    const int c = tid & 63;
    const int g = tid >> 6;

    // stage W2 in LDS, padded stride 65 (conflict-free matvec reads)
#pragma unroll
    for (int m = tid; m < 4096; m += 1024)
        W2L[(m >> 6) * 65 + (m & 63)] = W2[m];

    // cache this thread's 64 base values in registers
    float bl[64];
#pragma unroll
    for (int rr = 0; rr < 64; ++rr)
        bl[rr] = base[(size_t)(g * 64 + rr) * EE + c];

    if (tid < 64) sS[c] = 0.f;
    __syncthreads();

    for (int t = 0; t < 4; ++t) {
        if (tid < 64) {
            float v = b2[c];
#pragma unroll
            for (int k = 0; k < 64; ++k) v = fmaf(W2L[c * 65 + k], sS[k], v);
            sV[c] = v;
        }
        __syncthreads();
        float v2c = sV[c];
        float acc = 0.f;
#pragma unroll
        for (int rr = 0; rr < 64; ++rr) acc += fmaxf(bl[rr] + v2c, 0.f);
        sP[tid] = acc;
        __syncthreads();
        if (tid < 64) {
            float s = 0.f;
#pragma unroll
            for (int gg = 0; gg < 16; ++gg) s += sP[gg * 64 + c];
            sS[c] = s;
        }
        __syncthreads();
    }

    if (tid < 64) {
        float h = b6[c];
        for (int k = 0; k < 64; ++k) h = fmaf(W6[c * 64 + k], sS[k], h);
        float p = fmaxf(h, 0.f) * W5[c];
#pragma unroll
        for (int off = 32; off > 0; off >>= 1) p += __shfl_down(p, off, 64);
        v2out[c] = sV[c];
        if (tid == 0) Cout[0] = p;
    }
}

// K3: per-row epilogue. 4 rows per block (one wave per row).
__global__ __launch_bounds__(256) void k3_out(
    const float* __restrict__ base,
    const float* __restrict__ W7, const float* __restrict__ b7,
    const float* __restrict__ W5, const float* __restrict__ b5,
    const float* __restrict__ v2, const float* __restrict__ Cin,
    float* __restrict__ q)
{
    __shared__ float W7L[64 * 65];
    __shared__ float embL[4 * 64];
    const int tid = threadIdx.x;
    const int lane = tid & 63;
    const int rl = tid >> 6;
    const int i = blockIdx.x * 4 + rl;

    for (int m = tid; m < 4096; m += 256)
        W7L[(m >> 6) * 65 + (m & 63)] = W7[m];

    float ev = fmaxf(base[(size_t)i * EE + lane] + v2[lane], 0.f);
    embL[rl * 64 + lane] = ev;
    __syncthreads();

    float h = b7[lane];
#pragma unroll
    for (int k = 0; k < 64; ++k)
        h = fmaf(embL[rl * 64 + k], W7L[lane * 65 + k], h);
    float p = fmaxf(h, 0.f) * W5[64 + lane];
#pragma unroll
    for (int off = 32; off > 0; off >>= 1) p += __shfl_down(p, off, 64);
    if (lane == 0) q[i] = p + Cin[0] + b5[0];
}

extern "C" void kernel_launch(void* const* d_in, const int* in_sizes, int n_in,
                              void* d_out, int out_size, void* d_ws, size_t ws_size,
                              hipStream_t stream)
{
    (void)in_sizes; (void)n_in; (void)out_size; (void)ws_size;
    const float* nf   = (const float*)d_in[0];
    const float* cost = (const float*)d_in[1];
    const float* W1   = (const float*)d_in[2];
    const float* b1   = (const float*)d_in[3];
    const float* W2   = (const float*)d_in[4];
    const float* b2   = (const float*)d_in[5];
    const float* w4   = (const float*)d_in[6];
    const float* b4   = (const float*)d_in[7];
    const float* W5   = (const float*)d_in[8];
    const float* b5   = (const float*)d_in[9];
    const float* W6   = (const float*)d_in[10];
    const float* b6   = (const float*)d_in[11];
    const float* W7   = (const float*)d_in[12];
    const float* b7   = (const float*)d_in[13];
    float* q    = (float*)d_out;
    float* base = (float*)d_ws;            // N*E floats
    float* v2o  = base + (size_t)NN * EE;  // E floats
    float* Co   = v2o + EE;                // 1 float

    hipMemsetAsync(base, 0, (size_t)NN * EE * sizeof(float), stream);

    dim3 g1(32, 32);
    k1_base<<<g1, 256, 0, stream>>>(nf, cost, W1, b1, w4, b4, base);
    k2_scan<<<1, 1024, 0, stream>>>(base, W2, b2, W5, W6, b6, v2o, Co);
    k3_out<<<256, 256, 0, stream>>>(base, W7, b7, W5, b5, v2o, Co, q);
}

// Round 3
// 32.796 us; speedup vs baseline: 2.5870x; 2.3701x over previous
//
#include <hip/hip_runtime.h>

#define NN 1024
#define EE 64

// K1a: partial[jc][i][e] = sum_{j in chunk} relu(cost[j][i]*w4[e] + b4[e])
// grid (32 i-tiles, JCH j-chunks), block 256 = 32 i-lanes x 8 e-groups(8 e)
__global__ __launch_bounds__(256) void k1a_part(
    const float* __restrict__ cost,
    const float* __restrict__ w4, const float* __restrict__ b4,
    float* __restrict__ partial)
{
    const int it = blockIdx.x;
    const int jc = blockIdx.y;
    const int jspan = NN / gridDim.y;
    const int tid = threadIdx.x;
    const int il = tid & 31;
    const int eg = tid >> 5;          // 8 e-groups of 8
    const int i = it * 32 + il;
    const int j0 = jc * jspan;

    float w4v[8], b4v[8];
#pragma unroll
    for (int ee = 0; ee < 8; ++ee) {
        int e = eg * 8 + ee;
        w4v[ee] = w4[e];
        b4v[ee] = b4[e];
    }

    float acc[8];
#pragma unroll
    for (int ee = 0; ee < 8; ++ee) acc[ee] = 0.f;

    const float* cp = cost + (size_t)j0 * NN + i;
#pragma unroll 8
    for (int jj = 0; jj < jspan; ++jj) {
        float cv = cp[(size_t)jj * NN];
#pragma unroll
        for (int ee = 0; ee < 8; ++ee)
            acc[ee] += fmaxf(fmaf(cv, w4v[ee], b4v[ee]), 0.f);
    }

    float* dst = partial + ((size_t)jc * NN + i) * EE + eg * 8;
    float4 v0 = make_float4(acc[0], acc[1], acc[2], acc[3]);
    float4 v1 = make_float4(acc[4], acc[5], acc[6], acc[7]);
    *(float4*)(dst)     = v0;
    *(float4*)(dst + 4) = v1;
}

// K1b: base[i][e] = x[i]*W1[e] + b1[e] + sum_p partial[p][i][e]
__global__ __launch_bounds__(256) void k1b_reduce(
    const float* __restrict__ nf,
    const float* __restrict__ W1, const float* __restrict__ b1,
    const float* __restrict__ partial, int nparts,
    float* __restrict__ base)
{
    const int idx = blockIdx.x * 256 + threadIdx.x;  // 65536 total
    const int i = idx >> 6;
    const int e = idx & 63;
    float s0 = fmaf(nf[i], W1[e], b1[e]);
    float s1 = 0.f;
#pragma unroll 4
    for (int p = 0; p + 1 < nparts; p += 2) {
        s0 += partial[(size_t)p * (NN * EE) + idx];
        s1 += partial[(size_t)(p + 1) * (NN * EE) + idx];
    }
    if (nparts & 1) s0 += partial[(size_t)(nparts - 1) * (NN * EE) + idx];
    base[idx] = s0 + s1;
}

// K2: 4-step scan collapsed to E-vector recurrence; single 1024-thread block.
__global__ __launch_bounds__(1024) void k2_scan(
    const float* __restrict__ base,
    const float* __restrict__ W2, const float* __restrict__ b2,
    const float* __restrict__ W5,
    const float* __restrict__ W6, const float* __restrict__ b6,
    float* __restrict__ v2out, float* __restrict__ Cout)
{
    __shared__ float W2L[64 * 65];
    __shared__ float sP[1024];
    __shared__ float sS[64];
    __shared__ float sV[64];
    const int tid = threadIdx.x;
    const int c = tid & 63;
    const int g = tid >> 6;

#pragma unroll
    for (int m = tid; m < 4096; m += 1024)
        W2L[(m >> 6) * 65 + (m & 63)] = W2[m];

    float bl[64];
#pragma unroll
    for (int rr = 0; rr < 64; ++rr)
        bl[rr] = base[(size_t)(g * 64 + rr) * EE + c];

    if (tid < 64) sS[c] = 0.f;
    __syncthreads();

    for (int t = 0; t < 4; ++t) {
        if (tid < 64) {
            float v = b2[c];
#pragma unroll
            for (int k = 0; k < 64; ++k) v = fmaf(W2L[c * 65 + k], sS[k], v);
            sV[c] = v;
        }
        __syncthreads();
        float v2c = sV[c];
        float acc = 0.f;
#pragma unroll
        for (int rr = 0; rr < 64; ++rr) acc += fmaxf(bl[rr] + v2c, 0.f);
        sP[tid] = acc;
        __syncthreads();
        if (tid < 64) {
            float s = 0.f;
#pragma unroll
            for (int gg = 0; gg < 16; ++gg) s += sP[gg * 64 + c];
            sS[c] = s;
        }
        __syncthreads();
    }

    if (tid < 64) {
        float h = b6[c];
        for (int k = 0; k < 64; ++k) h = fmaf(W6[c * 64 + k], sS[k], h);
        float p = fmaxf(h, 0.f) * W5[c];
#pragma unroll
        for (int off = 32; off > 0; off >>= 1) p += __shfl_down(p, off, 64);
        v2out[c] = sV[c];
        if (tid == 0) Cout[0] = p;
    }
}

// K3: per-row epilogue. 4 rows per block (one wave per row).
__global__ __launch_bounds__(256) void k3_out(
    const float* __restrict__ base,
    const float* __restrict__ W7, const float* __restrict__ b7,
    const float* __restrict__ W5, const float* __restrict__ b5,
    const float* __restrict__ v2, const float* __restrict__ Cin,
    float* __restrict__ q)
{
    __shared__ float W7L[64 * 65];
    __shared__ float embL[4 * 64];
    const int tid = threadIdx.x;
    const int lane = tid & 63;
    const int rl = tid >> 6;
    const int i = blockIdx.x * 4 + rl;

    for (int m = tid; m < 4096; m += 256)
        W7L[(m >> 6) * 65 + (m & 63)] = W7[m];

    float ev = fmaxf(base[(size_t)i * EE + lane] + v2[lane], 0.f);
    embL[rl * 64 + lane] = ev;
    __syncthreads();

    float h = b7[lane];
#pragma unroll
    for (int k = 0; k < 64; ++k)
        h = fmaf(embL[rl * 64 + k], W7L[lane * 65 + k], h);
    float p = fmaxf(h, 0.f) * W5[64 + lane];
#pragma unroll
    for (int off = 32; off > 0; off >>= 1) p += __shfl_down(p, off, 64);
    if (lane == 0) q[i] = p + Cin[0] + b5[0];
}

extern "C" void kernel_launch(void* const* d_in, const int* in_sizes, int n_in,
                              void* d_out, int out_size, void* d_ws, size_t ws_size,
                              hipStream_t stream)
{
    (void)in_sizes; (void)n_in; (void)out_size;
    const float* nf   = (const float*)d_in[0];
    const float* cost = (const float*)d_in[1];
    const float* W1   = (const float*)d_in[2];
    const float* b1   = (const float*)d_in[3];
    const float* W2   = (const float*)d_in[4];
    const float* b2   = (const float*)d_in[5];
    const float* w4   = (const float*)d_in[6];
    const float* b4   = (const float*)d_in[7];
    const float* W5   = (const float*)d_in[8];
    const float* b5   = (const float*)d_in[9];
    const float* W6   = (const float*)d_in[10];
    const float* b6   = (const float*)d_in[11];
    const float* W7   = (const float*)d_in[12];
    const float* b7   = (const float*)d_in[13];
    float* q    = (float*)d_out;

    float* base = (float*)d_ws;              // NN*EE floats
    float* v2o  = base + (size_t)NN * EE;    // EE floats
    float* Co   = v2o + EE;                  // 1 float
    float* part = Co + 1;                    // nparts * NN*EE floats

    size_t fixed = ((size_t)NN * EE + EE + 1) * sizeof(float);
    size_t per_part = (size_t)NN * EE * sizeof(float);
    int nparts = 16;
    while (nparts > 1 && fixed + (size_t)nparts * per_part > ws_size) nparts >>= 1;

    dim3 g1(32, nparts);
    k1a_part<<<g1, 256, 0, stream>>>(cost, w4, b4, part);
    k1b_reduce<<<256, 256, 0, stream>>>(nf, W1, b1, part, nparts, base);
    k2_scan<<<1, 1024, 0, stream>>>(base, W2, b2, W5, W6, b6, v2o, Co);
    k3_out<<<256, 256, 0, stream>>>(base, W7, b7, W5, b5, v2o, Co, q);
}